// Round 3
// baseline (292.149 us; speedup 1.0000x reference)
//
#include <hip/hip_runtime.h>

// Volume renderer: alpha-compositing over 192 samples per ray.
// v4: TWO rays per wave + hard-fenced load clustering.
//
// Post-mortem v2/v3: VGPR_Count stayed 20 -- the compiler's pressure-
// minimizing scheduler serialized every load (load->wait->consume->reuse
// regs), leaving ~1 outstanding vmem op per wave. All three versions were
// the same serial latency chain => identical 103 us.
//
// v4 forces memory-level parallelism:
//  * 12x global_load_dwordx4 + 2 scalar loads issued back-to-back, then
//    __builtin_amdgcn_sched_barrier(0): a scheduling region boundary the
//    compiler cannot move loads across. All results must stay live
//    (VGPR ~60 expected -- if rocprof still shows 20, the fence failed).
//  * 2 rays per wave: doubles in-flight loads AND interleaves the two
//    rays' serial DPP-scan chains for free ILP. Ray B addresses fold into
//    ray A bases as immediate offsets (+768 B depth/sigma, +2304 B rgb).
//  * Lanes 48-63: clamped (duplicate-lane-47) addresses, no branches; all
//    loaded data finite, their weights zero-selected before reductions;
//    forward-only scan means they never affect lanes < 48.

#define NRAYS 65536
#define L 192
#define BORDER_W 1e10f
#define EPS_F 1e-10f

// DPP helper: invalid-source / masked-row lanes receive `old` (identity).
template <int CTRL, int RMASK>
__device__ __forceinline__ float updpp(float old, float src) {
    return __int_as_float(__builtin_amdgcn_update_dpp(
        __float_as_int(old), __float_as_int(src), CTRL, RMASK, 0xf, false));
}

// Inclusive product scan across the 64-lane wave (6 DPP VALU ops).
__device__ __forceinline__ float wave_incl_prod(float p) {
    p *= updpp<0x111, 0xf>(1.0f, p);  // row_shr:1
    p *= updpp<0x112, 0xf>(1.0f, p);  // row_shr:2
    p *= updpp<0x114, 0xf>(1.0f, p);  // row_shr:4
    p *= updpp<0x118, 0xf>(1.0f, p);  // row_shr:8
    p *= updpp<0x142, 0xa>(1.0f, p);  // row_bcast:15 -> rows 1,3
    p *= updpp<0x143, 0xc>(1.0f, p);  // row_bcast:31 -> rows 2,3
    return p;
}

// Inclusive sum scan: after this, lane 63 holds the wave total.
#define SUMSCAN(v)                          \
    v += updpp<0x111, 0xf>(0.0f, v);        \
    v += updpp<0x112, 0xf>(0.0f, v);        \
    v += updpp<0x114, 0xf>(0.0f, v);        \
    v += updpp<0x118, 0xf>(0.0f, v);        \
    v += updpp<0x142, 0xa>(0.0f, v);        \
    v += updpp<0x143, 0xc>(0.0f, v);

__device__ __forceinline__ float fast_sigmoid(float x) {
    return __builtin_amdgcn_rcpf(1.0f + __expf(-x));
}

__global__ __launch_bounds__(256) void vol_render_kernel(
    const float* __restrict__ depth,   // [N, 192]
    const float* __restrict__ rgb,     // [N, 192, 3]
    const float* __restrict__ sigma,   // [N, 192]
    float* __restrict__ out)           // color N*3 | depth N | acc N | weights N*192
{
    const int lane = threadIdx.x & 63;
    const int wave = threadIdx.x >> 6;
    const int rayA = blockIdx.x * 8 + wave * 2;   // 4 waves * 2 rays = 8 rays/block
    const int rayB = rayA + 1;

    const int  cl     = (lane < 48) ? lane : 47;       // clamped lane
    const bool active = lane < 48;
    const size_t lastIdx = (size_t)NRAYS * L - 1;

    const size_t sbaseA = (size_t)rayA * L + cl * 4;
    const size_t sbaseB = sbaseA + L;                  // ray B = +768 B
    const float* rpA = rgb + (size_t)rayA * (L * 3) + cl * 12;
    const float* rpB = rpA + L * 3;                    // +2304 B

    size_t i4A = sbaseA + 4; if (i4A > lastIdx) i4A = lastIdx;
    size_t i4B = sbaseB + 4; if (i4B > lastIdx) i4B = lastIdx;

    // ---- ALL loads issued back-to-back; fence stops the scheduler from
    //      sinking any of them to their uses ----
    float4 dvA = *reinterpret_cast<const float4*>(depth + sbaseA);
    float4 dvB = *reinterpret_cast<const float4*>(depth + sbaseB);
    float4 svA = *reinterpret_cast<const float4*>(sigma + sbaseA);
    float4 svB = *reinterpret_cast<const float4*>(sigma + sbaseB);
    float4 rA0 = *reinterpret_cast<const float4*>(rpA + 0);
    float4 rA1 = *reinterpret_cast<const float4*>(rpA + 4);
    float4 rA2 = *reinterpret_cast<const float4*>(rpA + 8);
    float4 rB0 = *reinterpret_cast<const float4*>(rpB + 0);
    float4 rB1 = *reinterpret_cast<const float4*>(rpB + 4);
    float4 rB2 = *reinterpret_cast<const float4*>(rpB + 8);
    float d4A = depth[i4A];
    float d4B = depth[i4B];
    __builtin_amdgcn_sched_barrier(0);

    // ---- alpha / survival (A and B interleaved by the scheduler) ----
    float e0A = __expf(-fmaxf(svA.x, 0.0f) * (dvA.y - dvA.x));
    float e1A = __expf(-fmaxf(svA.y, 0.0f) * (dvA.z - dvA.y));
    float e2A = __expf(-fmaxf(svA.z, 0.0f) * (dvA.w - dvA.z));
    float e3A = __expf(-fmaxf(svA.w, 0.0f) * ((lane == 47) ? BORDER_W : (d4A - dvA.w)));
    float e0B = __expf(-fmaxf(svB.x, 0.0f) * (dvB.y - dvB.x));
    float e1B = __expf(-fmaxf(svB.y, 0.0f) * (dvB.z - dvB.y));
    float e2B = __expf(-fmaxf(svB.z, 0.0f) * (dvB.w - dvB.z));
    float e3B = __expf(-fmaxf(svB.w, 0.0f) * ((lane == 47) ? BORDER_W : (d4B - dvB.w)));

    float sv0A = e0A + EPS_F, sv1A = e1A + EPS_F, sv2A = e2A + EPS_F, sv3A = e3A + EPS_F;
    float sv0B = e0B + EPS_F, sv1B = e1B + EPS_F, sv2B = e2B + EPS_F, sv3B = e3B + EPS_F;

    // in-lane prefix products
    float p01A = sv0A * sv1A, p012A = p01A * sv2A, pAllA = p012A * sv3A;
    float p01B = sv0B * sv1B, p012B = p01B * sv2B, pAllB = p012B * sv3B;

    // ---- two independent wave product scans (chains interleave) ----
    float pA = wave_incl_prod(pAllA);
    float pB = wave_incl_prod(pAllB);

    float exA = __shfl_up(pA, 1, 64);
    float exB = __shfl_up(pB, 1, 64);
    if (lane == 0) { exA = 1.0f; exB = 1.0f; }

    // transmittance & weights
    float w0A = (1.0f - e0A) * exA;
    float w1A = (1.0f - e1A) * exA * sv0A;
    float w2A = (1.0f - e2A) * exA * p01A;
    float w3A = (1.0f - e3A) * exA * p012A;
    float w0B = (1.0f - e0B) * exB;
    float w1B = (1.0f - e1B) * exB * sv0B;
    float w2B = (1.0f - e2B) * exB * p01B;
    float w3B = (1.0f - e3B) * exB * p012B;

    // inactive lanes (duplicated data) must not contribute
    if (!active) {
        w0A = w1A = w2A = w3A = 0.0f;
        w0B = w1B = w2B = w3B = 0.0f;
    }

    // coalesced float4 weight stores
    if (active) {
        *reinterpret_cast<float4*>(out + (size_t)NRAYS * 5 + sbaseA) =
            make_float4(w0A, w1A, w2A, w3A);
        *reinterpret_cast<float4*>(out + (size_t)NRAYS * 5 + sbaseB) =
            make_float4(w0B, w1B, w2B, w3B);
    }

    // sigmoids (independent -> fill latency slots)
    float g0A = fast_sigmoid(rA0.x), g1A = fast_sigmoid(rA0.y), g2A = fast_sigmoid(rA0.z);
    float g3A = fast_sigmoid(rA0.w), g4A = fast_sigmoid(rA1.x), g5A = fast_sigmoid(rA1.y);
    float g6A = fast_sigmoid(rA1.z), g7A = fast_sigmoid(rA1.w), g8A = fast_sigmoid(rA2.x);
    float g9A = fast_sigmoid(rA2.y), gAA = fast_sigmoid(rA2.z), gBA = fast_sigmoid(rA2.w);
    float g0B = fast_sigmoid(rB0.x), g1B = fast_sigmoid(rB0.y), g2B = fast_sigmoid(rB0.z);
    float g3B = fast_sigmoid(rB0.w), g4B = fast_sigmoid(rB1.x), g5B = fast_sigmoid(rB1.y);
    float g6B = fast_sigmoid(rB1.z), g7B = fast_sigmoid(rB1.w), g8B = fast_sigmoid(rB2.x);
    float g9B = fast_sigmoid(rB2.y), gAB = fast_sigmoid(rB2.z), gBB = fast_sigmoid(rB2.w);

    float c0A = w0A * g0A + w1A * g3A + w2A * g6A + w3A * g9A;
    float c1A = w0A * g1A + w1A * g4A + w2A * g7A + w3A * gAA;
    float c2A = w0A * g2A + w1A * g5A + w2A * g8A + w3A * gBA;
    float dpA = w0A * dvA.x + w1A * dvA.y + w2A * dvA.z + w3A * dvA.w;
    float acA = w0A + w1A + w2A + w3A;
    float c0B = w0B * g0B + w1B * g3B + w2B * g6B + w3B * g9B;
    float c1B = w0B * g1B + w1B * g4B + w2B * g7B + w3B * gAB;
    float c2B = w0B * g2B + w1B * g5B + w2B * g8B + w3B * gBB;
    float dpB = w0B * dvB.x + w1B * dvB.y + w2B * dvB.z + w3B * dvB.w;
    float acB = w0B + w1B + w2B + w3B;

    // ---- 10 independent DPP sum-scans; totals land in lane 63 ----
    SUMSCAN(c0A) SUMSCAN(c1A) SUMSCAN(c2A) SUMSCAN(dpA) SUMSCAN(acA)
    SUMSCAN(c0B) SUMSCAN(c1B) SUMSCAN(c2B) SUMSCAN(dpB) SUMSCAN(acB)

    if (lane == 63) {
        out[(size_t)rayA * 3 + 0] = c0A;
        out[(size_t)rayA * 3 + 1] = c1A;
        out[(size_t)rayA * 3 + 2] = c2A;
        out[(size_t)NRAYS * 3 + rayA] = dpA;
        out[(size_t)NRAYS * 4 + rayA] = acA;
        out[(size_t)rayB * 3 + 0] = c0B;
        out[(size_t)rayB * 3 + 1] = c1B;
        out[(size_t)rayB * 3 + 2] = c2B;
        out[(size_t)NRAYS * 3 + rayB] = dpB;
        out[(size_t)NRAYS * 4 + rayB] = acB;
    }
}

extern "C" void kernel_launch(void* const* d_in, const int* in_sizes, int n_in,
                              void* d_out, int out_size, void* d_ws, size_t ws_size,
                              hipStream_t stream) {
    const float* depth = (const float*)d_in[0];
    const float* rgb   = (const float*)d_in[1];
    const float* sigma = (const float*)d_in[2];
    float* out = (float*)d_out;

    // 4 waves/block, 2 rays/wave -> 8 rays per 256-thread block
    dim3 grid(NRAYS / 8);
    dim3 block(256);
    vol_render_kernel<<<grid, block, 0, stream>>>(depth, rgb, sigma, out);
}